// Round 1
// baseline (34.482 us; speedup 1.0000x reference)
//
#include <hip/hip_runtime.h>
#include <hip/hip_bf16.h>

// Tsit5 (Tsitouras 2011) coefficients
#define A21 0.161f
#define A31 (-0.008480655492356989f)
#define A32 0.335480655492357f
#define A41 2.8971530571054935f
#define A42 (-6.359448489975075f)
#define A43 4.3622954328695815f
#define A51 5.325864828439257f
#define A52 (-11.748883564062828f)
#define A53 7.4955393428898365f
#define A54 (-0.09249506636175525f)
#define A61 5.86145544294642f
#define A62 (-12.92096931784711f)
#define A63 8.159367898576159f
#define A64 (-0.071584973281401f)
#define A65 (-0.028269050394068383f)
#define B1 0.09646076681806523f
#define B2 0.01f
#define B3 0.4798896504144996f
#define B4 1.379008574103742f
#define B5 (-3.290069515436081f)
#define B6 2.324710524099774f

#define NORM 32768.0f
#define SUBSTEPS 8
#define IN_DIM 4096
#define OUT_DIM 1024

__global__ __launch_bounds__(256) void ODERamp_kernel(
    const float* __restrict__ in,      // [4096, 4096]
    const int* __restrict__ ng_ptr,    // scalar ngroups
    float* __restrict__ out)           // [ngroups, 1024, 1024]
{
    const int idx = blockIdx.x * blockDim.x + threadIdx.x;   // 0 .. 1024*1024-1
    const int r = idx >> 10;          // output row
    const int c = idx & 1023;         // output col

    // 4x4 block sum. Each thread reads 4 contiguous float4's; consecutive
    // lanes read consecutive 16B segments -> fully coalesced.
    float s = 0.0f;
#pragma unroll
    for (int i = 0; i < 4; ++i) {
        const float4 v = *reinterpret_cast<const float4*>(
            in + (size_t)(4 * r + i) * IN_DIM + 4 * c);
        s += (v.x + v.y) + (v.z + v.w);
    }

    const int ngroups = *ng_ptr;                 // uniform scalar load
    const float I  = s * (1.0f / NORM);
    const float dt = 1.0f / (float)(ngroups * SUBSTEPS);
    const float z  = I * dt;

    // Tsit5 stage polynomials for y' = I*(1-y):
    //   k_i = I*(1-y)*q_i(z), with q_1 = 1.
    const float q2 = 1.0f - A21 * z;
    const float q3 = 1.0f - z * (A31 + A32 * q2);
    const float q4 = 1.0f - z * (A41 + A42 * q2 + A43 * q3);
    const float q5 = 1.0f - z * (A51 + A52 * q2 + A53 * q3 + A54 * q4);
    const float q6 = 1.0f - z * (A61 + A62 * q2 + A63 * q3 + A64 * q4 + A65 * q5);
    const float R  = z * (B1 + B2 * q2 + B3 * q3 + B4 * q4 + B5 * q5 + B6 * q6);

    // One substep: (1 - y_new) = (1 - y) * f,  f = 1 - R(z).
    const float f  = 1.0f - R;
    const float f2 = f * f;
    const float f4 = f2 * f2;
    const float f8 = f4 * f4;                    // one saved group = 8 substeps

    float acc = 1.0f;                            // (1 - y) running product
    for (int g = 0; g < ngroups; ++g) {
        acc *= f8;
        out[(size_t)g * (OUT_DIM * OUT_DIM) + idx] = NORM * (1.0f - acc);
    }
}

extern "C" void kernel_launch(void* const* d_in, const int* in_sizes, int n_in,
                              void* d_out, int out_size, void* d_ws, size_t ws_size,
                              hipStream_t stream) {
    const float* illum = (const float*)d_in[0];
    const int* ng = (const int*)d_in[1];
    float* out = (float*)d_out;

    const int n_pix = OUT_DIM * OUT_DIM;         // 1,048,576
    const int block = 256;
    const int grid = n_pix / block;              // 4096 blocks

    ODERamp_kernel<<<grid, block, 0, stream>>>(illum, ng, out);
}